// Round 6
// baseline (342.667 us; speedup 1.0000x reference)
//
#include <hip/hip_runtime.h>
#include <math.h>

#define N_NODES 61440
#define N_EDGES 245760
#define BATCH   2048
#define ATOMS   30
#define F_LEN   64
#define DIM     256
#define NUM_NEI 32
#define MF      40
#define ECAP    512

typedef __attribute__((ext_vector_type(8))) short s8v;
typedef __attribute__((ext_vector_type(4))) float f4v;

__device__ __forceinline__ unsigned short f2bf(float x) {
    union { float f; unsigned u; } c; c.f = x;
    unsigned r = (c.u + 0x7FFFu + ((c.u >> 16) & 1u)) >> 16;
    return (unsigned short)r;
}
__device__ __forceinline__ float bf2f(unsigned short u) {
    union { unsigned u; float f; } c; c.u = ((unsigned)u) << 16;
    return c.f;
}

// ---------------- degree counts ----------------
__global__ void k_deg(const int* __restrict__ esrc, const int* __restrict__ edst,
                      int* deg_out, int* deg_in) {
    int e = blockIdx.x * 256 + threadIdx.x;
    if (e < N_EDGES) {
        atomicAdd(&deg_out[esrc[e]], 1);
        atomicAdd(&deg_in[edst[e]], 1);
    }
}

// ---------------- CSR segment allocation: wave prefix + 1 atomic/wave ----------------
__global__ void k_alloc(const int* __restrict__ deg_in, int* row_start, int* cursor,
                        int* counter) {
    int t = threadIdx.x;
    int n = blockIdx.x * 256 + t;
    int lane = t & 63;
    int d = deg_in[n];
    int p = d;
#pragma unroll
    for (int o = 1; o < 64; o <<= 1) { int v = __shfl_up(p, o, 64); if (lane >= o) p += v; }
    int base = 0;
    if (lane == 63) base = atomicAdd(counter, p);
    base = __shfl(base, 63, 64);
    int v = base + p - d;
    row_start[n] = v;
    cursor[n] = v;
}

__global__ void k_csr_fill(const int* __restrict__ esrc, const int* __restrict__ edst,
                           int* cursor, int* csr_src) {
    int e = blockIdx.x * 256 + threadIdx.x;
    if (e < N_EDGES) {
        int p = atomicAdd(&cursor[edst[e]], 1);
        csr_src[p] = esrc[e];
    }
}

// ---------------- weight prep: bf16 transposed copies ----------------
__global__ void k_prepw(const float* __restrict__ W0, const float* __restrict__ W1,
                        unsigned short* w0bt, unsigned short* w1bt) {
    int n = blockIdx.x, k = threadIdx.x;
    w1bt[(size_t)n * 256 + k] = f2bf(W1[(size_t)k * 256 + n]);
    if (k < 64) w0bt[(size_t)n * 64 + k] = f2bf(W0[(size_t)k * 256 + n]);
}

// ---------------- fused layer-0: CSR gather one-hot + MFMA gemm -> h1 bf16 ----------------
__global__ __launch_bounds__(256) void k_gcn0(
    const int* __restrict__ nf, const int* __restrict__ row_start,
    const int* __restrict__ csr_src, const int* __restrict__ deg_in,
    const int* __restrict__ deg_out, const unsigned short* __restrict__ w0bt,
    const float* __restrict__ b0, unsigned short* __restrict__ h1b) {
    __shared__ float la0[32 * 68];
    __shared__ int4  enf[ECAP];
    __shared__ float ens[ECAP];
    __shared__ int   rs[33];
    __shared__ float lnd[32], lns[32];
    __shared__ float b0c[256];
    int n0 = blockIdx.x * 32;
    int t = threadIdx.x;
    if (t < 32) rs[t] = row_start[n0 + t];
    if (t == 0) rs[32] = row_start[n0 + 31] + deg_in[n0 + 31];
    if (t < 32) {
        lnd[t] = rsqrtf((float)max(deg_in[n0 + t], 1));
        lns[t] = rsqrtf((float)max(deg_out[n0 + t], 1));
    }
    b0c[t] = b0[t];
    __syncthreads();
    int beg0 = rs[0];
    int tot = rs[32] - beg0; if (tot > ECAP) tot = ECAP;
    for (int e = t; e < tot; e += 256) {
        int s = csr_src[beg0 + e];
        enf[e] = ((const int4*)nf)[s];
        ens[e] = rsqrtf((float)max(deg_out[s], 1));
    }
    __syncthreads();
    {   // build la0[row][64] one-hot aggregate
        int row = t >> 3, kc = (t & 7) * 8;
        float a[8];
#pragma unroll
        for (int j = 0; j < 8; j++) a[j] = 0.f;
        int lo = rs[row] - beg0, hi = rs[row + 1] - beg0;
        if (hi > tot) hi = tot;
        for (int e = lo; e < hi; e++) {
            int4 f = enf[e]; float w = ens[e];
#pragma unroll
            for (int j = 0; j < 8; j++) {
                int k = kc + j;
                a[j] += w * (float)((f.x == k) + (f.y == k) + (f.z == k) + (f.w == k));
            }
        }
#pragma unroll
        for (int j = 0; j < 8; j++) la0[row * 68 + kc + j] = a[j];
    }
    __syncthreads();
    int lane = t & 63, wv = t >> 6;
    int ln = lane & 15, lg = lane >> 4;
    f4v acc[2][4];
#pragma unroll
    for (int mi = 0; mi < 2; mi++)
#pragma unroll
        for (int ni = 0; ni < 4; ni++) acc[mi][ni] = (f4v)0.f;
#pragma unroll
    for (int kst = 0; kst < 2; kst++) {
        s8v afr[2];
#pragma unroll
        for (int mi = 0; mi < 2; mi++) {
            const float* p = &la0[(mi * 16 + ln) * 68 + kst * 32 + lg * 8];
            f4v lo = *(const f4v*)p;
            f4v hi = *(const f4v*)(p + 4);
            s8v a;
#pragma unroll
            for (int j = 0; j < 4; j++) { a[j] = (short)f2bf(lo[j]); a[4 + j] = (short)f2bf(hi[j]); }
            afr[mi] = a;
        }
#pragma unroll
        for (int ni = 0; ni < 4; ni++) {
            int n = wv * 64 + ni * 16 + ln;
            s8v b = *(const s8v*)&w0bt[(size_t)n * 64 + kst * 32 + lg * 8];
            acc[0][ni] = __builtin_amdgcn_mfma_f32_16x16x32_bf16(afr[0], b, acc[0][ni], 0, 0, 0);
            acc[1][ni] = __builtin_amdgcn_mfma_f32_16x16x32_bf16(afr[1], b, acc[1][ni], 0, 0, 0);
        }
    }
#pragma unroll
    for (int mi = 0; mi < 2; mi++)
#pragma unroll
        for (int ni = 0; ni < 4; ni++) {
            int n = wv * 64 + ni * 16 + ln;
            float bb = b0c[n];
#pragma unroll
            for (int r = 0; r < 4; r++) {
                int m = mi * 16 + lg * 4 + r;
                float z = acc[mi][ni][r] * lnd[m] + bb;
                z = fmaxf(z, 0.f) * lns[m];
                h1b[(size_t)(n0 + m) * 256 + n] = f2bf(z);
            }
        }
}

// ---------------- fused layer-1: branchless gather + MFMA + norm + pooled atomics ----------------
__global__ __launch_bounds__(256) void k_gcn1(
    const unsigned short* __restrict__ h1b, const int* __restrict__ row_start,
    const int* __restrict__ csr_src, const int* __restrict__ deg_in,
    const int* __restrict__ graph_ids,
    const unsigned short* __restrict__ w1bt, const float* __restrict__ b1,
    float* __restrict__ pooled, float* __restrict__ partial) {
    __shared__ unsigned short lab[32 * 264];
    __shared__ int   ecache[ECAP];
    __shared__ int   rs[33];
    __shared__ float lnd[32];
    __shared__ float b1c[256];
    __shared__ float nsq[32];
    __shared__ int   gid[32];
    int n0 = blockIdx.x * 32;
    int t = threadIdx.x;
    if (t < 32) rs[t] = row_start[n0 + t];
    if (t == 0) rs[32] = row_start[n0 + 31] + deg_in[n0 + 31];
    if (t < 32) {
        lnd[t] = rsqrtf((float)max(deg_in[n0 + t], 1));
        nsq[t] = 0.f;
        gid[t] = graph_ids[n0 + t];
    }
    b1c[t] = b1[t];
    __syncthreads();
    int beg0 = rs[0];
    int tot = rs[32] - beg0; if (tot > ECAP) tot = ECAP;
    for (int e = t; e < tot; e += 256) ecache[e] = csr_src[beg0 + e];
    __syncthreads();
    // branchless gather: thread owns 8 cols x 4 interleaved rows, 8 loads in flight
    {
        int gr = t >> 5;             // row base 0..7
        int gc = (t & 31) * 8;       // column octet
        int lo[4], cnt[4];
#pragma unroll
        for (int r = 0; r < 4; r++) {
            int i = gr + r * 8;
            lo[r] = rs[i] - beg0;
            int h = rs[i + 1] - beg0; if (h > tot) h = tot;
            cnt[r] = h - lo[r];
        }
        float a[4][8];
#pragma unroll
        for (int r = 0; r < 4; r++)
#pragma unroll
            for (int j = 0; j < 8; j++) a[r][j] = 0.f;
        int mx = max(max(cnt[0], cnt[1]), max(cnt[2], cnt[3]));
        for (int it = 0; it < mx; it += 2) {
            int sidx[4][2]; float wm[4][2];
#pragma unroll
            for (int r = 0; r < 4; r++)
#pragma unroll
                for (int u = 0; u < 2; u++) {
                    bool val = (it + u) < cnt[r];
                    sidx[r][u] = ecache[val ? (lo[r] + it + u) : 0];
                    wm[r][u] = val ? 1.f : 0.f;
                }
            s8v v[4][2];
#pragma unroll
            for (int r = 0; r < 4; r++)
#pragma unroll
                for (int u = 0; u < 2; u++)
                    v[r][u] = *(const s8v*)&h1b[(size_t)sidx[r][u] * 256 + gc];
#pragma unroll
            for (int r = 0; r < 4; r++)
#pragma unroll
                for (int u = 0; u < 2; u++)
#pragma unroll
                    for (int j = 0; j < 8; j++)
                        a[r][j] = fmaf(wm[r][u], bf2f((unsigned short)v[r][u][j]), a[r][j]);
        }
#pragma unroll
        for (int r = 0; r < 4; r++) {
            int i = gr + r * 8;
            s8v ov;
#pragma unroll
            for (int j = 0; j < 8; j++) ov[j] = (short)f2bf(a[r][j]);
            *(s8v*)&lab[i * 264 + gc] = ov;
        }
    }
    __syncthreads();
    int lane = t & 63, wv = t >> 6;
    int ln = lane & 15, lg = lane >> 4;
    f4v acc[2][4];
#pragma unroll
    for (int mi = 0; mi < 2; mi++)
#pragma unroll
        for (int ni = 0; ni < 4; ni++) acc[mi][ni] = (f4v)0.f;
#pragma unroll 2
    for (int kst = 0; kst < 8; kst++) {
        s8v afr[2];
#pragma unroll
        for (int mi = 0; mi < 2; mi++)
            afr[mi] = *(const s8v*)&lab[(mi * 16 + ln) * 264 + kst * 32 + lg * 8];
#pragma unroll
        for (int ni = 0; ni < 4; ni++) {
            int n = wv * 64 + ni * 16 + ln;
            s8v b = *(const s8v*)&w1bt[(size_t)n * 256 + kst * 32 + lg * 8];
            acc[0][ni] = __builtin_amdgcn_mfma_f32_16x16x32_bf16(afr[0], b, acc[0][ni], 0, 0, 0);
            acc[1][ni] = __builtin_amdgcn_mfma_f32_16x16x32_bf16(afr[1], b, acc[1][ni], 0, 0, 0);
        }
    }
    float sm[2][4];
#pragma unroll
    for (int mi = 0; mi < 2; mi++)
#pragma unroll
        for (int r = 0; r < 4; r++) sm[mi][r] = 0.f;
#pragma unroll
    for (int mi = 0; mi < 2; mi++)
#pragma unroll
        for (int ni = 0; ni < 4; ni++) {
            int n = wv * 64 + ni * 16 + ln;
            float bb = b1c[n];
#pragma unroll
            for (int r = 0; r < 4; r++) {
                int m = mi * 16 + lg * 4 + r;
                float z = acc[mi][ni][r] * lnd[m] + bb;
                atomicAdd(&pooled[(size_t)gid[m] * 256 + n], z);
                sm[mi][r] += z * z;
            }
        }
#pragma unroll
    for (int mi = 0; mi < 2; mi++)
#pragma unroll
        for (int r = 0; r < 4; r++) {
            float v = sm[mi][r];
            v += __shfl_xor(v, 1);
            v += __shfl_xor(v, 2);
            v += __shfl_xor(v, 4);
            v += __shfl_xor(v, 8);
            if (ln == 0) atomicAdd(&nsq[mi * 16 + lg * 4 + r], v);
        }
    __syncthreads();
    if (t < 32) atomicAdd(&partial[(n0 + t) & 1023], sqrtf(nsq[t]));
}

// ---------------- norm finish ----------------
__global__ void k_normfin(const float* __restrict__ partial, float* factor) {
    __shared__ float red[256];
    int t = threadIdx.x;
    float s = partial[t] + partial[t + 256] + partial[t + 512] + partial[t + 768];
    red[t] = s;
    __syncthreads();
    for (int o = 128; o; o >>= 1) {
        if (t < o) red[t] += red[t + o];
        __syncthreads();
    }
    if (t == 0) factor[0] = 16.0f / (red[0] / (float)N_NODES);
}

// ---------------- fused reaction: pool-out + target + attention(s=0,1) + crosscl ----------------
__global__ __launch_bounds__(256) void k_rxn(
    const int* __restrict__ id_list, const int* __restrict__ id_list_t,
    const int* __restrict__ neimat, const float* __restrict__ mfea,
    const float* __restrict__ fea_emb, const float* __restrict__ att_w,
    const float* __restrict__ att_b, const float* __restrict__ crosscl_w,
    const float* __restrict__ crosscl_b, const float* __restrict__ pooled,
    const float* __restrict__ factor, float* __restrict__ out) {
    __shared__ float com[MF];
    __shared__ float mitem[MF];
    __shared__ float u[DIM];
    __shared__ float nm[NUM_NEI * MF];
    __shared__ float vv[MF];
    __shared__ float aw[NUM_NEI];
    __shared__ float mre[DIM];
    int b = blockIdx.x;
    int t = threadIdx.x;
    int wv = t >> 6, lane = t & 63;
    // atom-pool output (fp32 pooled x factor)
    float pv = pooled[(size_t)b * 256 + t] * factor[0];
    out[(size_t)b * 512 + t] = pv;                            // mol_embedding[:, :256]
    out[(size_t)BATCH * 512 + (size_t)b * DIM + t] = pv;      // mol_atom_embedding
    if (t < MF) {
        int i0 = id_list[b], i1 = id_list[BATCH + b];
        int j0 = id_list_t[b], j1 = id_list_t[BATCH + b];
        com[t] = 0.5f * (mfea[(size_t)i0 * MF + t] + mfea[(size_t)i1 * MF + t])
               + 0.5f * (mfea[(size_t)j0 * MF + t] + mfea[(size_t)j1 * MF + t]);
    }
    __syncthreads();
    float tg = 0.f;
    for (int f = 0; f < MF; f++) tg += com[f] * fea_emb[f * DIM + t];
    float awt = att_w[t];
    float msum = 0.f;
    for (int s = 0; s < 2; s++) {
        int id = id_list[s * BATCH + b];
        __syncthreads();             // protect nm/vv/aw reuse across s
        if (t < MF) mitem[t] = mfea[(size_t)id * MF + t];
        for (int i = t; i < NUM_NEI * MF; i += 256) {
            int k = i / MF, f = i - k * MF;
            int nid = neimat[(size_t)id * NUM_NEI + k];
            nm[i] = mfea[(size_t)nid * MF + f];
        }
        __syncthreads();
        float item = 0.f;
        for (int f = 0; f < MF; f++) item += mitem[f] * fea_emb[f * DIM + t];
        u[t] = item * tg * awt;
        __syncthreads();
        for (int i = 0; i < 5; i++) {
            int f = wv + 8 * i;
            float p = 0.f;
#pragma unroll
            for (int j = 0; j < 4; j++) p += u[lane + 64 * j] * fea_emb[f * DIM + lane + 64 * j];
#pragma unroll
            for (int off = 32; off; off >>= 1) p += __shfl_down(p, off, 64);
            if (lane == 0) vv[f] = p;
        }
        __syncthreads();
        if (wv == 0) {
            float lg = -1e30f;
            if (lane < NUM_NEI) {
                lg = att_b[0];
                for (int f = 0; f < MF; f++) lg += nm[lane * MF + f] * vv[f];
            }
            float m = lg;
#pragma unroll
            for (int off = 16; off; off >>= 1) m = fmaxf(m, __shfl_xor(m, off, 32));
            float e = (lane < NUM_NEI) ? __expf(lg - m) : 0.f;
            float ssum = e;
#pragma unroll
            for (int off = 16; off; off >>= 1) ssum += __shfl_xor(ssum, off, 32);
            if (lane < NUM_NEI) aw[lane] = e / ssum;
        }
        __syncthreads();
        if (t < MF) {
            float w = 0.f;
            for (int k = 0; k < NUM_NEI; k++) w += aw[k] * nm[k * MF + t];
            vv[t] = w;
        }
        __syncthreads();
        float na = 0.f;
        for (int f = 0; f < MF; f++) na += vv[f] * fea_emb[f * DIM + t];
        msum += item + na;
    }
    float m = 0.5f * msum;
    out[(size_t)b * 512 + DIM + t] = m;          // mol_embedding[:, 256:]
    mre[t] = m;
    __syncthreads();
    float acc = crosscl_b[t];
    for (int uu = 0; uu < DIM; uu++) acc += mre[uu] * crosscl_w[uu * DIM + t];
    out[(size_t)BATCH * 768 + (size_t)b * DIM + t] = acc;   // mol_x_embedding
}

extern "C" void kernel_launch(void* const* d_in, const int* in_sizes, int n_in,
                              void* d_out, int out_size, void* d_ws, size_t ws_size,
                              hipStream_t stream) {
    const int*   node_feat = (const int*)d_in[0];
    const int*   edge_src  = (const int*)d_in[1];
    const int*   edge_dst  = (const int*)d_in[2];
    const int*   graph_ids = (const int*)d_in[3];
    const int*   id_list   = (const int*)d_in[4];
    const int*   id_list_t = (const int*)d_in[5];
    const float* all_mfea  = (const float*)d_in[6];
    const int*   neimat    = (const int*)d_in[7];
    const float* W0        = (const float*)d_in[8];
    const float* b0        = (const float*)d_in[9];
    const float* W1        = (const float*)d_in[10];
    const float* b1        = (const float*)d_in[11];
    const float* fea_emb   = (const float*)d_in[12];
    const float* att_w     = (const float*)d_in[13];
    const float* att_b     = (const float*)d_in[14];
    const float* crosscl_w = (const float*)d_in[15];
    const float* crosscl_b = (const float*)d_in[16];
    float* out = (float*)d_out;

    char* ws = (char*)d_ws;
    char* zbase = ws;
    int*   deg_out   = (int*)ws;            ws += (size_t)N_NODES * 4;
    int*   deg_in    = (int*)ws;            ws += (size_t)N_NODES * 4;
    float* partial   = (float*)ws;          ws += 1024 * 4;
    float* factor    = (float*)ws;
    int*   counter   = (int*)(ws + 8);      ws += 256;
    float* pooled    = (float*)ws;          ws += (size_t)BATCH * 256 * 4;
    size_t zbytes = (size_t)(ws - zbase);
    int*   row_start = (int*)ws;            ws += (size_t)N_NODES * 4;
    int*   cursor    = (int*)ws;            ws += (size_t)N_NODES * 4;
    int*   csr_srcb  = (int*)ws;            ws += (size_t)N_EDGES * 4;
    unsigned short* w0bt = (unsigned short*)ws; ws += (size_t)256 * 64 * 2;
    unsigned short* w1bt = (unsigned short*)ws; ws += (size_t)256 * 256 * 2;
    unsigned short* h1b  = (unsigned short*)ws; ws += (size_t)N_NODES * DIM * 2;

    hipMemsetAsync(zbase, 0, zbytes, stream);

    k_deg<<<(N_EDGES + 255) / 256, 256, 0, stream>>>(edge_src, edge_dst, deg_out, deg_in);
    k_alloc<<<N_NODES / 256, 256, 0, stream>>>(deg_in, row_start, cursor, counter);
    k_csr_fill<<<(N_EDGES + 255) / 256, 256, 0, stream>>>(edge_src, edge_dst, cursor, csr_srcb);
    k_prepw<<<256, 256, 0, stream>>>(W0, W1, w0bt, w1bt);

    k_gcn0<<<N_NODES / 32, 256, 0, stream>>>(node_feat, row_start, csr_srcb, deg_in,
                                             deg_out, w0bt, b0, h1b);
    k_gcn1<<<N_NODES / 32, 256, 0, stream>>>(h1b, row_start, csr_srcb, deg_in, graph_ids,
                                             w1bt, b1, pooled, partial);
    k_normfin<<<1, 256, 0, stream>>>(partial, factor);
    k_rxn<<<BATCH, 256, 0, stream>>>(id_list, id_list_t, neimat, all_mfea, fea_emb,
                                     att_w, att_b, crosscl_w, crosscl_b, pooled,
                                     factor, out);
}

// Round 7
// 190.998 us; speedup vs baseline: 1.7941x; 1.7941x over previous
//
#include <hip/hip_runtime.h>
#include <math.h>

#define N_NODES 61440
#define N_EDGES 245760
#define BATCH   2048
#define ATOMS   30
#define F_LEN   64
#define DIM     256
#define NUM_NEI 32
#define MF      40
#define ECAP    512
#define CHUNK   64

typedef __attribute__((ext_vector_type(8))) short s8v;
typedef __attribute__((ext_vector_type(4))) float f4v;
typedef __attribute__((address_space(3))) unsigned lds_u32;
typedef const __attribute__((address_space(1))) unsigned glb_u32;

__device__ __forceinline__ unsigned short f2bf(float x) {
    union { float f; unsigned u; } c; c.f = x;
    unsigned r = (c.u + 0x7FFFu + ((c.u >> 16) & 1u)) >> 16;
    return (unsigned short)r;
}
__device__ __forceinline__ float bf2f(unsigned short u) {
    union { unsigned u; float f; } c; c.u = ((unsigned)u) << 16;
    return c.f;
}

// ---------------- degree counts ----------------
__global__ void k_deg(const int* __restrict__ esrc, const int* __restrict__ edst,
                      int* deg_out, int* deg_in) {
    int e = blockIdx.x * 256 + threadIdx.x;
    if (e < N_EDGES) {
        atomicAdd(&deg_out[esrc[e]], 1);
        atomicAdd(&deg_in[edst[e]], 1);
    }
}

// ---------------- CSR segment allocation: wave prefix + 1 atomic/wave ----------------
__global__ void k_alloc(const int* __restrict__ deg_in, int* row_start, int* cursor,
                        int* counter) {
    int t = threadIdx.x;
    int n = blockIdx.x * 256 + t;
    int lane = t & 63;
    int d = deg_in[n];
    int p = d;
#pragma unroll
    for (int o = 1; o < 64; o <<= 1) { int v = __shfl_up(p, o, 64); if (lane >= o) p += v; }
    int base = 0;
    if (lane == 63) base = atomicAdd(counter, p);
    base = __shfl(base, 63, 64);
    int v = base + p - d;
    row_start[n] = v;
    cursor[n] = v;
}

__global__ void k_csr_fill(const int* __restrict__ esrc, const int* __restrict__ edst,
                           int* cursor, int* csr_src) {
    int e = blockIdx.x * 256 + threadIdx.x;
    if (e < N_EDGES) {
        int p = atomicAdd(&cursor[edst[e]], 1);
        csr_src[p] = esrc[e];
    }
}

// ---------------- weight prep: bf16 transposed copies ----------------
__global__ void k_prepw(const float* __restrict__ W0, const float* __restrict__ W1,
                        unsigned short* w0bt, unsigned short* w1bt) {
    int n = blockIdx.x, k = threadIdx.x;
    w1bt[(size_t)n * 256 + k] = f2bf(W1[(size_t)k * 256 + n]);
    if (k < 64) w0bt[(size_t)n * 64 + k] = f2bf(W0[(size_t)k * 256 + n]);
}

// ---------------- fused layer-0: CSR gather one-hot + MFMA gemm -> h1 bf16 ----------------
__global__ __launch_bounds__(256) void k_gcn0(
    const int* __restrict__ nf, const int* __restrict__ row_start,
    const int* __restrict__ csr_src, const int* __restrict__ deg_in,
    const int* __restrict__ deg_out, const unsigned short* __restrict__ w0bt,
    const float* __restrict__ b0, unsigned short* __restrict__ h1b) {
    __shared__ float la0[32 * 68];
    __shared__ int4  enf[ECAP];
    __shared__ float ens[ECAP];
    __shared__ int   rs[33];
    __shared__ float lnd[32], lns[32];
    __shared__ float b0c[256];
    int n0 = blockIdx.x * 32;
    int t = threadIdx.x;
    if (t < 32) rs[t] = row_start[n0 + t];
    if (t == 0) rs[32] = row_start[n0 + 31] + deg_in[n0 + 31];
    if (t < 32) {
        lnd[t] = rsqrtf((float)max(deg_in[n0 + t], 1));
        lns[t] = rsqrtf((float)max(deg_out[n0 + t], 1));
    }
    b0c[t] = b0[t];
    __syncthreads();
    int beg0 = rs[0];
    int tot = rs[32] - beg0; if (tot > ECAP) tot = ECAP;
    for (int e = t; e < tot; e += 256) {
        int s = csr_src[beg0 + e];
        enf[e] = ((const int4*)nf)[s];
        ens[e] = rsqrtf((float)max(deg_out[s], 1));
    }
    __syncthreads();
    {   // build la0[row][64] one-hot aggregate
        int row = t >> 3, kc = (t & 7) * 8;
        float a[8];
#pragma unroll
        for (int j = 0; j < 8; j++) a[j] = 0.f;
        int lo = rs[row] - beg0, hi = rs[row + 1] - beg0;
        if (hi > tot) hi = tot;
        for (int e = lo; e < hi; e++) {
            int4 f = enf[e]; float w = ens[e];
#pragma unroll
            for (int j = 0; j < 8; j++) {
                int k = kc + j;
                a[j] += w * (float)((f.x == k) + (f.y == k) + (f.z == k) + (f.w == k));
            }
        }
#pragma unroll
        for (int j = 0; j < 8; j++) la0[row * 68 + kc + j] = a[j];
    }
    __syncthreads();
    int lane = t & 63, wv = t >> 6;
    int ln = lane & 15, lg = lane >> 4;
    f4v acc[2][4];
#pragma unroll
    for (int mi = 0; mi < 2; mi++)
#pragma unroll
        for (int ni = 0; ni < 4; ni++) acc[mi][ni] = (f4v)0.f;
#pragma unroll
    for (int kst = 0; kst < 2; kst++) {
        s8v afr[2];
#pragma unroll
        for (int mi = 0; mi < 2; mi++) {
            const float* p = &la0[(mi * 16 + ln) * 68 + kst * 32 + lg * 8];
            f4v lo = *(const f4v*)p;
            f4v hi = *(const f4v*)(p + 4);
            s8v a;
#pragma unroll
            for (int j = 0; j < 4; j++) { a[j] = (short)f2bf(lo[j]); a[4 + j] = (short)f2bf(hi[j]); }
            afr[mi] = a;
        }
#pragma unroll
        for (int ni = 0; ni < 4; ni++) {
            int n = wv * 64 + ni * 16 + ln;
            s8v b = *(const s8v*)&w0bt[(size_t)n * 64 + kst * 32 + lg * 8];
            acc[0][ni] = __builtin_amdgcn_mfma_f32_16x16x32_bf16(afr[0], b, acc[0][ni], 0, 0, 0);
            acc[1][ni] = __builtin_amdgcn_mfma_f32_16x16x32_bf16(afr[1], b, acc[1][ni], 0, 0, 0);
        }
    }
#pragma unroll
    for (int mi = 0; mi < 2; mi++)
#pragma unroll
        for (int ni = 0; ni < 4; ni++) {
            int n = wv * 64 + ni * 16 + ln;
            float bb = b0c[n];
#pragma unroll
            for (int r = 0; r < 4; r++) {
                int m = mi * 16 + lg * 4 + r;
                float z = acc[mi][ni][r] * lnd[m] + bb;
                z = fmaxf(z, 0.f) * lns[m];
                h1b[(size_t)(n0 + m) * 256 + n] = f2bf(z);
            }
        }
}

// ---------------- fused layer-1: global_load_lds staged gather + MFMA + norm -> h2 bf16 ----------------
__global__ __launch_bounds__(256) void k_gcn1(
    const unsigned short* __restrict__ h1b, const int* __restrict__ row_start,
    const int* __restrict__ csr_src, const int* __restrict__ deg_in,
    const unsigned short* __restrict__ w1bt, const float* __restrict__ b1,
    unsigned short* __restrict__ h2b, float* __restrict__ partial) {
    __shared__ unsigned short stage[CHUNK * 256];   // 32 KB: staged edge rows
    __shared__ unsigned short lab[32 * 264];
    __shared__ int   ecache[ECAP];
    __shared__ int   rs[33];
    __shared__ float lnd[32];
    __shared__ float b1c[256];
    __shared__ float nsq[32];
    int n0 = blockIdx.x * 32;
    int t = threadIdx.x;
    int lane = t & 63, wv = t >> 6;
    if (t < 32) rs[t] = row_start[n0 + t];
    if (t == 0) rs[32] = row_start[n0 + 31] + deg_in[n0 + 31];
    if (t < 32) {
        lnd[t] = rsqrtf((float)max(deg_in[n0 + t], 1));
        nsq[t] = 0.f;
    }
    b1c[t] = b1[t];
    __syncthreads();
    int beg0 = rs[0];
    int tot = rs[32] - beg0; if (tot > ECAP) tot = ECAP;
    for (int e = t; e < tot; e += 256) ecache[e] = csr_src[beg0 + e];
    __syncthreads();
    // chunked staged gather: 1 global_load_lds = 2 edge rows (64 lanes x 16B)
    int gr = t >> 5;               // row group 0..7
    int gc = (t & 31) * 8;         // column octet
    int lo[4], hi[4];
#pragma unroll
    for (int r = 0; r < 4; r++) {
        int i = gr + r * 8;
        lo[r] = rs[i] - beg0;
        int h = rs[i + 1] - beg0; if (h > tot) h = tot;
        hi[r] = h;
    }
    float a[4][8];
#pragma unroll
    for (int r = 0; r < 4; r++)
#pragma unroll
        for (int j = 0; j < 8; j++) a[r][j] = 0.f;
    int lhalf = (lane >> 5) & 1;
    for (int c0 = 0; c0 < tot; c0 += CHUNK) {
        int nch = min(CHUNK, tot - c0);
        int npair = (nch + 1) >> 1;
        for (int p = wv; p < npair; p += 4) {
            int e = c0 + 2 * p + lhalf;
            int ecl = min(e, tot - 1);
            int sv = ecache[ecl];
            const unsigned short* src = h1b + (size_t)sv * 256 + (lane & 31) * 8;
            __builtin_amdgcn_global_load_lds((glb_u32*)src,
                                             (lds_u32*)&stage[(size_t)(2 * p) * 256],
                                             16, 0, 0);
        }
        asm volatile("s_waitcnt vmcnt(0)" ::: "memory");
        __syncthreads();
#pragma unroll
        for (int r = 0; r < 4; r++) {
            int es = max(lo[r], c0) - c0;
            int ee = min(hi[r], c0 + nch) - c0;
            for (int e = es; e < ee; e++) {
                s8v v = *(const s8v*)&stage[e * 256 + gc];
#pragma unroll
                for (int j = 0; j < 8; j++) a[r][j] += bf2f((unsigned short)v[j]);
            }
        }
        __syncthreads();   // before next chunk overwrites stage
    }
#pragma unroll
    for (int r = 0; r < 4; r++) {
        int i = gr + r * 8;
        s8v ov;
#pragma unroll
        for (int j = 0; j < 8; j++) ov[j] = (short)f2bf(a[r][j]);
        *(s8v*)&lab[i * 264 + gc] = ov;
    }
    __syncthreads();
    int ln = lane & 15, lg = lane >> 4;
    f4v acc[2][4];
#pragma unroll
    for (int mi = 0; mi < 2; mi++)
#pragma unroll
        for (int ni = 0; ni < 4; ni++) acc[mi][ni] = (f4v)0.f;
#pragma unroll 2
    for (int kst = 0; kst < 8; kst++) {
        s8v afr[2];
#pragma unroll
        for (int mi = 0; mi < 2; mi++)
            afr[mi] = *(const s8v*)&lab[(mi * 16 + ln) * 264 + kst * 32 + lg * 8];
#pragma unroll
        for (int ni = 0; ni < 4; ni++) {
            int n = wv * 64 + ni * 16 + ln;
            s8v b = *(const s8v*)&w1bt[(size_t)n * 256 + kst * 32 + lg * 8];
            acc[0][ni] = __builtin_amdgcn_mfma_f32_16x16x32_bf16(afr[0], b, acc[0][ni], 0, 0, 0);
            acc[1][ni] = __builtin_amdgcn_mfma_f32_16x16x32_bf16(afr[1], b, acc[1][ni], 0, 0, 0);
        }
    }
    float sm[2][4];
#pragma unroll
    for (int mi = 0; mi < 2; mi++)
#pragma unroll
        for (int r = 0; r < 4; r++) sm[mi][r] = 0.f;
#pragma unroll
    for (int mi = 0; mi < 2; mi++)
#pragma unroll
        for (int ni = 0; ni < 4; ni++) {
            int n = wv * 64 + ni * 16 + ln;
            float bb = b1c[n];
#pragma unroll
            for (int r = 0; r < 4; r++) {
                int m = mi * 16 + lg * 4 + r;
                float z = acc[mi][ni][r] * lnd[m] + bb;
                h2b[(size_t)(n0 + m) * 256 + n] = f2bf(z);
                sm[mi][r] += z * z;
            }
        }
#pragma unroll
    for (int mi = 0; mi < 2; mi++)
#pragma unroll
        for (int r = 0; r < 4; r++) {
            float v = sm[mi][r];
            v += __shfl_xor(v, 1);
            v += __shfl_xor(v, 2);
            v += __shfl_xor(v, 4);
            v += __shfl_xor(v, 8);
            if (ln == 0) atomicAdd(&nsq[mi * 16 + lg * 4 + r], v);
        }
    __syncthreads();
    if (t < 32) atomicAdd(&partial[(n0 + t) & 1023], sqrtf(nsq[t]));
}

// ---------------- norm finish ----------------
__global__ void k_normfin(const float* __restrict__ partial, float* factor) {
    __shared__ float red[256];
    int t = threadIdx.x;
    float s = partial[t] + partial[t + 256] + partial[t + 512] + partial[t + 768];
    red[t] = s;
    __syncthreads();
    for (int o = 128; o; o >>= 1) {
        if (t < o) red[t] += red[t + o];
        __syncthreads();
    }
    if (t == 0) factor[0] = 16.0f / (red[0] / (float)N_NODES);
}

// ---------------- fused reaction: pool + target + attention(s=0,1) + crosscl ----------------
__global__ __launch_bounds__(256) void k_rxn(
    const int* __restrict__ id_list, const int* __restrict__ id_list_t,
    const int* __restrict__ neimat, const float* __restrict__ mfea,
    const float* __restrict__ fea_emb, const float* __restrict__ att_w,
    const float* __restrict__ att_b, const float* __restrict__ crosscl_w,
    const float* __restrict__ crosscl_b, const unsigned short* __restrict__ h2b,
    const float* __restrict__ factor, float* __restrict__ out) {
    __shared__ float com[MF];
    __shared__ float mitem[MF];
    __shared__ float u[DIM];
    __shared__ float nm[NUM_NEI * MF];
    __shared__ float vv[MF];
    __shared__ float aw[NUM_NEI];
    __shared__ float mre[DIM];
    int b = blockIdx.x;
    int t = threadIdx.x;
    int wv = t >> 6, lane = t & 63;
    // atom-pool: sum 30 rows of h2b for this graph
    float pv = 0.f;
    for (int a = 0; a < ATOMS; a++) pv += bf2f(h2b[(size_t)(b * ATOMS + a) * DIM + t]);
    pv *= factor[0];
    out[(size_t)b * 512 + t] = pv;                            // mol_embedding[:, :256]
    out[(size_t)BATCH * 512 + (size_t)b * DIM + t] = pv;      // mol_atom_embedding
    if (t < MF) {
        int i0 = id_list[b], i1 = id_list[BATCH + b];
        int j0 = id_list_t[b], j1 = id_list_t[BATCH + b];
        com[t] = 0.5f * (mfea[(size_t)i0 * MF + t] + mfea[(size_t)i1 * MF + t])
               + 0.5f * (mfea[(size_t)j0 * MF + t] + mfea[(size_t)j1 * MF + t]);
    }
    __syncthreads();
    float tg = 0.f;
    for (int f = 0; f < MF; f++) tg += com[f] * fea_emb[f * DIM + t];
    float awt = att_w[t];
    float msum = 0.f;
    for (int s = 0; s < 2; s++) {
        int id = id_list[s * BATCH + b];
        __syncthreads();             // protect nm/vv/aw reuse across s
        if (t < MF) mitem[t] = mfea[(size_t)id * MF + t];
        for (int i = t; i < NUM_NEI * MF; i += 256) {
            int k = i / MF, f = i - k * MF;
            int nid = neimat[(size_t)id * NUM_NEI + k];
            nm[i] = mfea[(size_t)nid * MF + f];
        }
        __syncthreads();
        float item = 0.f;
        for (int f = 0; f < MF; f++) item += mitem[f] * fea_emb[f * DIM + t];
        u[t] = item * tg * awt;
        __syncthreads();
        for (int i = 0; i < 5; i++) {
            int f = wv + 8 * i;
            float p = 0.f;
#pragma unroll
            for (int j = 0; j < 4; j++) p += u[lane + 64 * j] * fea_emb[f * DIM + lane + 64 * j];
#pragma unroll
            for (int off = 32; off; off >>= 1) p += __shfl_down(p, off, 64);
            if (lane == 0) vv[f] = p;
        }
        __syncthreads();
        if (wv == 0) {
            float lg = -1e30f;
            if (lane < NUM_NEI) {
                lg = att_b[0];
                for (int f = 0; f < MF; f++) lg += nm[lane * MF + f] * vv[f];
            }
            float m = lg;
#pragma unroll
            for (int off = 16; off; off >>= 1) m = fmaxf(m, __shfl_xor(m, off, 32));
            float e = (lane < NUM_NEI) ? __expf(lg - m) : 0.f;
            float ssum = e;
#pragma unroll
            for (int off = 16; off; off >>= 1) ssum += __shfl_xor(ssum, off, 32);
            if (lane < NUM_NEI) aw[lane] = e / ssum;
        }
        __syncthreads();
        if (t < MF) {
            float w = 0.f;
            for (int k = 0; k < NUM_NEI; k++) w += aw[k] * nm[k * MF + t];
            vv[t] = w;
        }
        __syncthreads();
        float na = 0.f;
        for (int f = 0; f < MF; f++) na += vv[f] * fea_emb[f * DIM + t];
        msum += item + na;
    }
    float m = 0.5f * msum;
    out[(size_t)b * 512 + DIM + t] = m;          // mol_embedding[:, 256:]
    mre[t] = m;
    __syncthreads();
    float acc = crosscl_b[t];
    for (int uu = 0; uu < DIM; uu++) acc += mre[uu] * crosscl_w[uu * DIM + t];
    out[(size_t)BATCH * 768 + (size_t)b * DIM + t] = acc;   // mol_x_embedding
}

extern "C" void kernel_launch(void* const* d_in, const int* in_sizes, int n_in,
                              void* d_out, int out_size, void* d_ws, size_t ws_size,
                              hipStream_t stream) {
    const int*   node_feat = (const int*)d_in[0];
    const int*   edge_src  = (const int*)d_in[1];
    const int*   edge_dst  = (const int*)d_in[2];
    const int*   id_list   = (const int*)d_in[4];
    const int*   id_list_t = (const int*)d_in[5];
    const float* all_mfea  = (const float*)d_in[6];
    const int*   neimat    = (const int*)d_in[7];
    const float* W0        = (const float*)d_in[8];
    const float* b0        = (const float*)d_in[9];
    const float* W1        = (const float*)d_in[10];
    const float* b1        = (const float*)d_in[11];
    const float* fea_emb   = (const float*)d_in[12];
    const float* att_w     = (const float*)d_in[13];
    const float* att_b     = (const float*)d_in[14];
    const float* crosscl_w = (const float*)d_in[15];
    const float* crosscl_b = (const float*)d_in[16];
    float* out = (float*)d_out;

    char* ws = (char*)d_ws;
    char* zbase = ws;
    int*   deg_out   = (int*)ws;            ws += (size_t)N_NODES * 4;
    int*   deg_in    = (int*)ws;            ws += (size_t)N_NODES * 4;
    float* partial   = (float*)ws;          ws += 1024 * 4;
    float* factor    = (float*)ws;
    int*   counter   = (int*)(ws + 8);      ws += 256;
    size_t zbytes = (size_t)(ws - zbase);
    int*   row_start = (int*)ws;            ws += (size_t)N_NODES * 4;
    int*   cursor    = (int*)ws;            ws += (size_t)N_NODES * 4;
    int*   csr_srcb  = (int*)ws;            ws += (size_t)N_EDGES * 4;
    unsigned short* w0bt = (unsigned short*)ws; ws += (size_t)256 * 64 * 2;
    unsigned short* w1bt = (unsigned short*)ws; ws += (size_t)256 * 256 * 2;
    unsigned short* h1b  = (unsigned short*)ws; ws += (size_t)N_NODES * DIM * 2;
    unsigned short* h2b  = (unsigned short*)ws; ws += (size_t)N_NODES * DIM * 2;

    hipMemsetAsync(zbase, 0, zbytes, stream);

    k_deg<<<(N_EDGES + 255) / 256, 256, 0, stream>>>(edge_src, edge_dst, deg_out, deg_in);
    k_alloc<<<N_NODES / 256, 256, 0, stream>>>(deg_in, row_start, cursor, counter);
    k_csr_fill<<<(N_EDGES + 255) / 256, 256, 0, stream>>>(edge_src, edge_dst, cursor, csr_srcb);
    k_prepw<<<256, 256, 0, stream>>>(W0, W1, w0bt, w1bt);

    k_gcn0<<<N_NODES / 32, 256, 0, stream>>>(node_feat, row_start, csr_srcb, deg_in,
                                             deg_out, w0bt, b0, h1b);
    k_gcn1<<<N_NODES / 32, 256, 0, stream>>>(h1b, row_start, csr_srcb, deg_in,
                                             w1bt, b1, h2b, partial);
    k_normfin<<<1, 256, 0, stream>>>(partial, factor);
    k_rxn<<<BATCH, 256, 0, stream>>>(id_list, id_list_t, neimat, all_mfea, fea_emb,
                                     att_w, att_b, crosscl_w, crosscl_b, h2b,
                                     factor, out);
}

// Round 8
// 179.613 us; speedup vs baseline: 1.9078x; 1.0634x over previous
//
#include <hip/hip_runtime.h>
#include <math.h>

#define N_NODES 61440
#define N_EDGES 245760
#define BATCH   2048
#define ATOMS   30
#define F_LEN   64
#define DIM     256
#define NUM_NEI 32
#define MF      40
#define ECAP    512
#define CH      32          // edges per pipeline chunk

typedef __attribute__((ext_vector_type(8))) short s8v;
typedef __attribute__((ext_vector_type(4))) float f4v;
typedef __attribute__((address_space(3))) unsigned lds_u32;
typedef const __attribute__((address_space(1))) unsigned glb_u32;

__device__ __forceinline__ unsigned short f2bf(float x) {
    union { float f; unsigned u; } c; c.f = x;
    unsigned r = (c.u + 0x7FFFu + ((c.u >> 16) & 1u)) >> 16;
    return (unsigned short)r;
}
__device__ __forceinline__ float bf2f(unsigned short u) {
    union { unsigned u; float f; } c; c.u = ((unsigned)u) << 16;
    return c.f;
}

// ---------------- degree counts ----------------
__global__ void k_deg(const int* __restrict__ esrc, const int* __restrict__ edst,
                      int* deg_out, int* deg_in) {
    int e = blockIdx.x * 256 + threadIdx.x;
    if (e < N_EDGES) {
        atomicAdd(&deg_out[esrc[e]], 1);
        atomicAdd(&deg_in[edst[e]], 1);
    }
}

// ---------------- CSR segment allocation: wave prefix + 1 atomic/wave ----------------
__global__ void k_alloc(const int* __restrict__ deg_in, int* row_start, int* cursor,
                        int* counter) {
    int t = threadIdx.x;
    int n = blockIdx.x * 256 + t;
    int lane = t & 63;
    int d = deg_in[n];
    int p = d;
#pragma unroll
    for (int o = 1; o < 64; o <<= 1) { int v = __shfl_up(p, o, 64); if (lane >= o) p += v; }
    int base = 0;
    if (lane == 63) base = atomicAdd(counter, p);
    base = __shfl(base, 63, 64);
    int v = base + p - d;
    row_start[n] = v;
    cursor[n] = v;
}

__global__ void k_csr_fill(const int* __restrict__ esrc, const int* __restrict__ edst,
                           int* cursor, int* csr_src) {
    int e = blockIdx.x * 256 + threadIdx.x;
    if (e < N_EDGES) {
        int p = atomicAdd(&cursor[edst[e]], 1);
        csr_src[p] = esrc[e];
    }
}

// ---------------- weight prep: tiled transpose to bf16 ----------------
// blocks 0..15: W1 (256x256) tiles; blocks 16..19: W0 (64x256) tiles
__global__ __launch_bounds__(256) void k_prepw(
    const float* __restrict__ W0, const float* __restrict__ W1,
    unsigned short* __restrict__ w0bt, unsigned short* __restrict__ w1bt) {
    __shared__ float tile[64][65];
    int bi = blockIdx.x;
    int t = threadIdx.x;
    int c = t & 63, rq = t >> 6;
    if (bi < 16) {
        int tr = bi >> 2, tc = bi & 3;        // k-tile, n-tile
#pragma unroll 4
        for (int pass = 0; pass < 16; pass++) {
            int r = rq + 4 * pass;
            tile[r][c] = W1[(size_t)(tr * 64 + r) * 256 + tc * 64 + c];
        }
        __syncthreads();
#pragma unroll 4
        for (int pass = 0; pass < 16; pass++) {
            int nr = rq + 4 * pass;
            w1bt[(size_t)(tc * 64 + nr) * 256 + tr * 64 + c] = f2bf(tile[c][nr]);
        }
    } else {
        int tb = bi - 16;                     // n-tile of W0
#pragma unroll 4
        for (int pass = 0; pass < 16; pass++) {
            int r = rq + 4 * pass;            // k row
            tile[r][c] = W0[(size_t)r * 256 + tb * 64 + c];
        }
        __syncthreads();
#pragma unroll 4
        for (int pass = 0; pass < 16; pass++) {
            int nr = rq + 4 * pass;
            w0bt[(size_t)(tb * 64 + nr) * 64 + c] = f2bf(tile[c][nr]);
        }
    }
}

// ---------------- fused layer-0: CSR gather one-hot + MFMA gemm -> h1 bf16 ----------------
__global__ __launch_bounds__(256) void k_gcn0(
    const int* __restrict__ nf, const int* __restrict__ row_start,
    const int* __restrict__ csr_src, const int* __restrict__ deg_in,
    const int* __restrict__ deg_out, const unsigned short* __restrict__ w0bt,
    const float* __restrict__ b0, unsigned short* __restrict__ h1b) {
    __shared__ float la0[32 * 68];
    __shared__ int4  enf[ECAP];
    __shared__ float ens[ECAP];
    __shared__ int   rs[33];
    __shared__ float lnd[32], lns[32];
    __shared__ float b0c[256];
    int n0 = blockIdx.x * 32;
    int t = threadIdx.x;
    if (t < 32) rs[t] = row_start[n0 + t];
    if (t == 0) rs[32] = row_start[n0 + 31] + deg_in[n0 + 31];
    if (t < 32) {
        lnd[t] = rsqrtf((float)max(deg_in[n0 + t], 1));
        lns[t] = rsqrtf((float)max(deg_out[n0 + t], 1));
    }
    b0c[t] = b0[t];
    __syncthreads();
    int beg0 = rs[0];
    int tot = rs[32] - beg0; if (tot > ECAP) tot = ECAP;
    for (int e = t; e < tot; e += 256) {
        int s = csr_src[beg0 + e];
        enf[e] = ((const int4*)nf)[s];
        ens[e] = rsqrtf((float)max(deg_out[s], 1));
    }
    __syncthreads();
    {   // build la0[row][64] one-hot aggregate
        int row = t >> 3, kc = (t & 7) * 8;
        float a[8];
#pragma unroll
        for (int j = 0; j < 8; j++) a[j] = 0.f;
        int lo = rs[row] - beg0, hi = rs[row + 1] - beg0;
        if (hi > tot) hi = tot;
        for (int e = lo; e < hi; e++) {
            int4 f = enf[e]; float w = ens[e];
#pragma unroll
            for (int j = 0; j < 8; j++) {
                int k = kc + j;
                a[j] += w * (float)((f.x == k) + (f.y == k) + (f.z == k) + (f.w == k));
            }
        }
#pragma unroll
        for (int j = 0; j < 8; j++) la0[row * 68 + kc + j] = a[j];
    }
    __syncthreads();
    int lane = t & 63, wv = t >> 6;
    int ln = lane & 15, lg = lane >> 4;
    f4v acc[2][4];
#pragma unroll
    for (int mi = 0; mi < 2; mi++)
#pragma unroll
        for (int ni = 0; ni < 4; ni++) acc[mi][ni] = (f4v)0.f;
#pragma unroll
    for (int kst = 0; kst < 2; kst++) {
        s8v afr[2];
#pragma unroll
        for (int mi = 0; mi < 2; mi++) {
            const float* p = &la0[(mi * 16 + ln) * 68 + kst * 32 + lg * 8];
            f4v lo = *(const f4v*)p;
            f4v hi = *(const f4v*)(p + 4);
            s8v a;
#pragma unroll
            for (int j = 0; j < 4; j++) { a[j] = (short)f2bf(lo[j]); a[4 + j] = (short)f2bf(hi[j]); }
            afr[mi] = a;
        }
#pragma unroll
        for (int ni = 0; ni < 4; ni++) {
            int n = wv * 64 + ni * 16 + ln;
            s8v b = *(const s8v*)&w0bt[(size_t)n * 64 + kst * 32 + lg * 8];
            acc[0][ni] = __builtin_amdgcn_mfma_f32_16x16x32_bf16(afr[0], b, acc[0][ni], 0, 0, 0);
            acc[1][ni] = __builtin_amdgcn_mfma_f32_16x16x32_bf16(afr[1], b, acc[1][ni], 0, 0, 0);
        }
    }
#pragma unroll
    for (int mi = 0; mi < 2; mi++)
#pragma unroll
        for (int ni = 0; ni < 4; ni++) {
            int n = wv * 64 + ni * 16 + ln;
            float bb = b0c[n];
#pragma unroll
            for (int r = 0; r < 4; r++) {
                int m = mi * 16 + lg * 4 + r;
                float z = acc[mi][ni][r] * lnd[m] + bb;
                z = fmaxf(z, 0.f) * lns[m];
                h1b[(size_t)(n0 + m) * 256 + n] = f2bf(z);
            }
        }
}

// ---------------- fused layer-1: dbuf counted-vmcnt staged gather + MFMA + norm ----------------
__global__ __launch_bounds__(256, 4) void k_gcn1(
    const unsigned short* __restrict__ h1b, const int* __restrict__ row_start,
    const int* __restrict__ csr_src, const int* __restrict__ deg_in,
    const unsigned short* __restrict__ w1bt, const float* __restrict__ b1,
    unsigned short* __restrict__ h2b, float* __restrict__ partial) {
    __shared__ unsigned short stage[2 * CH * 256];   // 32 KB dbuf; lab overlays buf0
    __shared__ int   ecache[ECAP];
    __shared__ int   rs[33];
    __shared__ float lnd[32];
    __shared__ float b1c[256];
    __shared__ float nsq[32];
    unsigned short* lab = stage;                     // 32*264 shorts, reused post-gather
    int n0 = blockIdx.x * 32;
    int t = threadIdx.x;
    int lane = t & 63, wv = t >> 6;
    if (t < 32) rs[t] = row_start[n0 + t];
    if (t == 0) rs[32] = row_start[n0 + 31] + deg_in[n0 + 31];
    if (t < 32) {
        lnd[t] = rsqrtf((float)max(deg_in[n0 + t], 1));
        nsq[t] = 0.f;
    }
    b1c[t] = b1[t];
    __syncthreads();
    int beg0 = rs[0];
    int tot = rs[32] - beg0; if (tot > ECAP) tot = ECAP;
    for (int e = t; e < tot; e += 256) ecache[e] = csr_src[beg0 + e];
    __syncthreads();

    int gr = t >> 5;               // dst row group 0..7
    int gc = (t & 31) * 8;         // column octet
    int lo[4], hi[4];
#pragma unroll
    for (int r = 0; r < 4; r++) {
        int i = gr + r * 8;
        lo[r] = rs[i] - beg0;
        int h = rs[i + 1] - beg0; if (h > tot) h = tot;
        hi[r] = h;
    }
    float a[4][8];
#pragma unroll
    for (int r = 0; r < 4; r++)
#pragma unroll
        for (int j = 0; j < 8; j++) a[r][j] = 0.f;

    int lhalf = lane >> 5;         // 0/1: which row of the pair this lane stages
    int colo = (lane & 31) * 8;    // staged column octet
    int nc = (tot + CH - 1) >> 5;  // number of 32-edge chunks
    // ISSUE(c): exactly 4 global_load_lds per wave (padded), buffer c&1
#define ISSUE(c)                                                                   \
    {                                                                              \
        int base_ = (c) << 5;                                                      \
        unsigned short* sb_ = stage + ((c) & 1) * (CH * 256);                      \
        _Pragma("unroll")                                                          \
        for (int pp = 0; pp < 4; ++pp) {                                           \
            int p_ = wv + pp * 4;                                                  \
            int e_ = base_ + 2 * p_ + lhalf;                                       \
            int sv_ = ecache[min(e_, tot - 1)];                                    \
            __builtin_amdgcn_global_load_lds(                                      \
                (glb_u32*)(h1b + (size_t)sv_ * 256 + colo),                        \
                (lds_u32*)(sb_ + 2 * p_ * 256), 16, 0, 0);                         \
        }                                                                          \
    }
    if (nc > 0) ISSUE(0);
    for (int c = 0; c < nc; ++c) {
        if (c + 1 < nc) {
            ISSUE(c + 1);
            asm volatile("s_waitcnt vmcnt(4)" ::: "memory");
        } else {
            asm volatile("s_waitcnt vmcnt(0)" ::: "memory");
        }
        __builtin_amdgcn_sched_barrier(0);
        __builtin_amdgcn_s_barrier();      // raw barrier: no vmcnt(0) drain
        int c0 = c << 5;
        int nch = min(CH, tot - c0);
        const unsigned short* sb = stage + (c & 1) * (CH * 256);
#pragma unroll
        for (int r = 0; r < 4; r++) {
            int es = max(lo[r] - c0, 0);
            int ee = min(hi[r] - c0, nch);
            for (int e = es; e < ee; e++) {
                s8v v = *(const s8v*)&sb[e * 256 + gc];
#pragma unroll
                for (int j = 0; j < 8; j++) a[r][j] += bf2f((unsigned short)v[j]);
            }
        }
        __builtin_amdgcn_s_barrier();      // all reads done before buffer reuse
    }
#undef ISSUE
#pragma unroll
    for (int r = 0; r < 4; r++) {
        int i = gr + r * 8;
        s8v ov;
#pragma unroll
        for (int j = 0; j < 8; j++) ov[j] = (short)f2bf(a[r][j]);
        *(s8v*)&lab[i * 264 + gc] = ov;
    }
    __syncthreads();
    int ln = lane & 15, lg = lane >> 4;
    f4v acc[2][4];
#pragma unroll
    for (int mi = 0; mi < 2; mi++)
#pragma unroll
        for (int ni = 0; ni < 4; ni++) acc[mi][ni] = (f4v)0.f;
#pragma unroll 2
    for (int kst = 0; kst < 8; kst++) {
        s8v afr[2];
#pragma unroll
        for (int mi = 0; mi < 2; mi++)
            afr[mi] = *(const s8v*)&lab[(mi * 16 + ln) * 264 + kst * 32 + lg * 8];
#pragma unroll
        for (int ni = 0; ni < 4; ni++) {
            int n = wv * 64 + ni * 16 + ln;
            s8v b = *(const s8v*)&w1bt[(size_t)n * 256 + kst * 32 + lg * 8];
            acc[0][ni] = __builtin_amdgcn_mfma_f32_16x16x32_bf16(afr[0], b, acc[0][ni], 0, 0, 0);
            acc[1][ni] = __builtin_amdgcn_mfma_f32_16x16x32_bf16(afr[1], b, acc[1][ni], 0, 0, 0);
        }
    }
    float sm[2][4];
#pragma unroll
    for (int mi = 0; mi < 2; mi++)
#pragma unroll
        for (int r = 0; r < 4; r++) sm[mi][r] = 0.f;
#pragma unroll
    for (int mi = 0; mi < 2; mi++)
#pragma unroll
        for (int ni = 0; ni < 4; ni++) {
            int n = wv * 64 + ni * 16 + ln;
            float bb = b1c[n];
#pragma unroll
            for (int r = 0; r < 4; r++) {
                int m = mi * 16 + lg * 4 + r;
                float z = acc[mi][ni][r] * lnd[m] + bb;
                h2b[(size_t)(n0 + m) * 256 + n] = f2bf(z);
                sm[mi][r] += z * z;
            }
        }
#pragma unroll
    for (int mi = 0; mi < 2; mi++)
#pragma unroll
        for (int r = 0; r < 4; r++) {
            float v = sm[mi][r];
            v += __shfl_xor(v, 1);
            v += __shfl_xor(v, 2);
            v += __shfl_xor(v, 4);
            v += __shfl_xor(v, 8);
            if (ln == 0) atomicAdd(&nsq[mi * 16 + lg * 4 + r], v);
        }
    __syncthreads();
    if (t < 32) atomicAdd(&partial[(n0 + t) & 1023], sqrtf(nsq[t]));
}

// ---------------- norm finish ----------------
__global__ void k_normfin(const float* __restrict__ partial, float* factor) {
    __shared__ float red[256];
    int t = threadIdx.x;
    float s = partial[t] + partial[t + 256] + partial[t + 512] + partial[t + 768];
    red[t] = s;
    __syncthreads();
    for (int o = 128; o; o >>= 1) {
        if (t < o) red[t] += red[t + o];
        __syncthreads();
    }
    if (t == 0) factor[0] = 16.0f / (red[0] / (float)N_NODES);
}

// ---------------- fused reaction: pool + target + attention(s=0,1) + crosscl ----------------
__global__ __launch_bounds__(256) void k_rxn(
    const int* __restrict__ id_list, const int* __restrict__ id_list_t,
    const int* __restrict__ neimat, const float* __restrict__ mfea,
    const float* __restrict__ fea_emb, const float* __restrict__ att_w,
    const float* __restrict__ att_b, const float* __restrict__ crosscl_w,
    const float* __restrict__ crosscl_b, const unsigned short* __restrict__ h2b,
    const float* __restrict__ factor, float* __restrict__ out) {
    __shared__ float com[MF];
    __shared__ float mitem[MF];
    __shared__ float u[DIM];
    __shared__ float nm[NUM_NEI * MF];
    __shared__ float vv[MF];
    __shared__ float aw[NUM_NEI];
    __shared__ float mre[DIM];
    int b = blockIdx.x;
    int t = threadIdx.x;
    int wv = t >> 6, lane = t & 63;
    // atom-pool: sum 30 rows of h2b for this graph
    float pv = 0.f;
    for (int a = 0; a < ATOMS; a++) pv += bf2f(h2b[(size_t)(b * ATOMS + a) * DIM + t]);
    pv *= factor[0];
    out[(size_t)b * 512 + t] = pv;                            // mol_embedding[:, :256]
    out[(size_t)BATCH * 512 + (size_t)b * DIM + t] = pv;      // mol_atom_embedding
    if (t < MF) {
        int i0 = id_list[b], i1 = id_list[BATCH + b];
        int j0 = id_list_t[b], j1 = id_list_t[BATCH + b];
        com[t] = 0.5f * (mfea[(size_t)i0 * MF + t] + mfea[(size_t)i1 * MF + t])
               + 0.5f * (mfea[(size_t)j0 * MF + t] + mfea[(size_t)j1 * MF + t]);
    }
    __syncthreads();
    float tg = 0.f;
    for (int f = 0; f < MF; f++) tg += com[f] * fea_emb[f * DIM + t];
    float awt = att_w[t];
    float msum = 0.f;
    for (int s = 0; s < 2; s++) {
        int id = id_list[s * BATCH + b];
        __syncthreads();             // protect nm/vv/aw reuse across s
        if (t < MF) mitem[t] = mfea[(size_t)id * MF + t];
        // float4 staging of 32 neighbor rows (40 floats each)
        for (int i = t; i < NUM_NEI * 10; i += 256) {
            int k = i / 10, q = i - k * 10;
            int nid = neimat[(size_t)id * NUM_NEI + k];
            *(float4*)&nm[k * MF + q * 4] = *(const float4*)&mfea[(size_t)nid * MF + q * 4];
        }
        __syncthreads();
        float item = 0.f;
        for (int f = 0; f < MF; f++) item += mitem[f] * fea_emb[f * DIM + t];
        u[t] = item * tg * awt;
        __syncthreads();
        for (int i = 0; i < 5; i++) {
            int f = wv + 8 * i;
            float p = 0.f;
#pragma unroll
            for (int j = 0; j < 4; j++) p += u[lane + 64 * j] * fea_emb[f * DIM + lane + 64 * j];
#pragma unroll
            for (int off = 32; off; off >>= 1) p += __shfl_down(p, off, 64);
            if (lane == 0) vv[f] = p;
        }
        __syncthreads();
        if (wv == 0) {
            float lg = -1e30f;
            if (lane < NUM_NEI) {
                lg = att_b[0];
                for (int f = 0; f < MF; f++) lg += nm[lane * MF + f] * vv[f];
            }
            float m = lg;
#pragma unroll
            for (int off = 16; off; off >>= 1) m = fmaxf(m, __shfl_xor(m, off, 32));
            float e = (lane < NUM_NEI) ? __expf(lg - m) : 0.f;
            float ssum = e;
#pragma unroll
            for (int off = 16; off; off >>= 1) ssum += __shfl_xor(ssum, off, 32);
            if (lane < NUM_NEI) aw[lane] = e / ssum;
        }
        __syncthreads();
        if (t < MF) {
            float w = 0.f;
            for (int k = 0; k < NUM_NEI; k++) w += aw[k] * nm[k * MF + t];
            vv[t] = w;
        }
        __syncthreads();
        float na = 0.f;
        for (int f = 0; f < MF; f++) na += vv[f] * fea_emb[f * DIM + t];
        msum += item + na;
    }
    float m = 0.5f * msum;
    out[(size_t)b * 512 + DIM + t] = m;          // mol_embedding[:, 256:]
    mre[t] = m;
    __syncthreads();
    float acc = crosscl_b[t];
    for (int uu = 0; uu < DIM; uu++) acc += mre[uu] * crosscl_w[uu * DIM + t];
    out[(size_t)BATCH * 768 + (size_t)b * DIM + t] = acc;   // mol_x_embedding
}

extern "C" void kernel_launch(void* const* d_in, const int* in_sizes, int n_in,
                              void* d_out, int out_size, void* d_ws, size_t ws_size,
                              hipStream_t stream) {
    const int*   node_feat = (const int*)d_in[0];
    const int*   edge_src  = (const int*)d_in[1];
    const int*   edge_dst  = (const int*)d_in[2];
    const int*   id_list   = (const int*)d_in[4];
    const int*   id_list_t = (const int*)d_in[5];
    const float* all_mfea  = (const float*)d_in[6];
    const int*   neimat    = (const int*)d_in[7];
    const float* W0        = (const float*)d_in[8];
    const float* b0        = (const float*)d_in[9];
    const float* W1        = (const float*)d_in[10];
    const float* b1        = (const float*)d_in[11];
    const float* fea_emb   = (const float*)d_in[12];
    const float* att_w     = (const float*)d_in[13];
    const float* att_b     = (const float*)d_in[14];
    const float* crosscl_w = (const float*)d_in[15];
    const float* crosscl_b = (const float*)d_in[16];
    float* out = (float*)d_out;

    char* ws = (char*)d_ws;
    char* zbase = ws;
    int*   deg_out   = (int*)ws;            ws += (size_t)N_NODES * 4;
    int*   deg_in    = (int*)ws;            ws += (size_t)N_NODES * 4;
    float* partial   = (float*)ws;          ws += 1024 * 4;
    float* factor    = (float*)ws;
    int*   counter   = (int*)(ws + 8);      ws += 256;
    size_t zbytes = (size_t)(ws - zbase);
    int*   row_start = (int*)ws;            ws += (size_t)N_NODES * 4;
    int*   cursor    = (int*)ws;            ws += (size_t)N_NODES * 4;
    int*   csr_srcb  = (int*)ws;            ws += (size_t)N_EDGES * 4;
    unsigned short* w0bt = (unsigned short*)ws; ws += (size_t)256 * 64 * 2;
    unsigned short* w1bt = (unsigned short*)ws; ws += (size_t)256 * 256 * 2;
    unsigned short* h1b  = (unsigned short*)ws; ws += (size_t)N_NODES * DIM * 2;
    unsigned short* h2b  = (unsigned short*)ws; ws += (size_t)N_NODES * DIM * 2;

    hipMemsetAsync(zbase, 0, zbytes, stream);

    k_deg<<<(N_EDGES + 255) / 256, 256, 0, stream>>>(edge_src, edge_dst, deg_out, deg_in);
    k_alloc<<<N_NODES / 256, 256, 0, stream>>>(deg_in, row_start, cursor, counter);
    k_csr_fill<<<(N_EDGES + 255) / 256, 256, 0, stream>>>(edge_src, edge_dst, cursor, csr_srcb);
    k_prepw<<<20, 256, 0, stream>>>(W0, W1, w0bt, w1bt);

    k_gcn0<<<N_NODES / 32, 256, 0, stream>>>(node_feat, row_start, csr_srcb, deg_in,
                                             deg_out, w0bt, b0, h1b);
    k_gcn1<<<N_NODES / 32, 256, 0, stream>>>(h1b, row_start, csr_srcb, deg_in,
                                             w1bt, b1, h2b, partial);
    k_normfin<<<1, 256, 0, stream>>>(partial, factor);
    k_rxn<<<BATCH, 256, 0, stream>>>(id_list, id_list_t, neimat, all_mfea, fea_emb,
                                     att_w, att_b, crosscl_w, crosscl_b, h2b,
                                     factor, out);
}